// Round 13
// baseline (29.439 us; speedup 1.0000x reference)
//
#include <hip/hip_runtime.h>
#include <hip/hip_bf16.h>

// Additive attention weights: B=2,H=4,LQ=LKV=512,D=64, fp32 in/out.
//   tanh(x) = 1 - 2/(1+e^{2x});  softmax drops uniform shift (sum w + b_logit)
//   => logit ~ sum_e w'_e/(1+e^{2x_e}),  w' = -2w,  x = qp+kp+b
//   e^{2x} = EQ*EK,  EQ=2^{(qp+b)*2log2e}, EK=2^{kp*2log2e}  (precomputed)
// 4-way rational combine over e (1 rcp per 4 e-terms). EK TRANSPOSED
// [bh][e][k]. R13 = R8 math/staging, occupancy doubled: 2048 blocks,
// 2 q-rows/block, thread rect 2 rows x 2 k (f32x2 loads) -> VGPR small
// enough for 8 blocks/CU (8 waves/SIMD, 2x latency hiding). No
// launch_bounds waves-arg (R6/R7: forced 64-VGPR clamp + scratch spill).

#define NQROWS 4096   // B*H*LQ

typedef float f32x2 __attribute__((ext_vector_type(2)));

__device__ __forceinline__ f32x2 fma2(f32x2 a, f32x2 b, f32x2 c) {
  return __builtin_elementwise_fma(a, b, c);
}
__device__ __forceinline__ f32x2 s2(float x) { return (f32x2){x, x}; }

// ---------------- kernel A: projections + exp2 ----------------
// 8 rows/block: blocks [0,512) Q rows, [512,1024) K rows. 4 waves/block.
__global__ __launch_bounds__(256) void proj_kernel(
    const float* __restrict__ Q, const float* __restrict__ K,
    const float* __restrict__ W, const float* __restrict__ bC,
    float* __restrict__ eq, float* __restrict__ ekt)
{
  const int t  = threadIdx.x;
  const int tr = t >> 6;        // 0..3
  const int e  = t & 63;
  const int rbase = blockIdx.x * 8;
  const bool isK = rbase >= NQROWS;
  const int r0 = isK ? rbase - NQROWS : rbase;
  const float* __restrict__ src = isK ? K : Q;
  const int off = isK ? 64 : 0;

  __shared__ float  srow[8][64];     // 2KB
  __shared__ float4 wsh[64][16];     // 16KB, XOR-swizzled (f4 col ^ (row&7))
  __shared__ float  trsp[64][9];     // 2.3KB, K-store transpose (pad 9)

  for (int i = t; i < 8 * 64; i += 256)
    srow[i >> 6][i & 63] = src[(r0 + (i >> 6)) * 64 + (i & 63)];
  for (int i = t; i < 64 * 16; i += 256) {
    const int er = i >> 4, d4 = i & 15;
    wsh[er][d4 ^ (er & 7)] =
        reinterpret_cast<const float4*>(W + er * 128 + off)[d4];
  }
  __syncthreads();

  float acc0 = 0.f, acc1 = 0.f;
  const int rA = tr * 2;
  #pragma unroll
  for (int d4 = 0; d4 < 16; ++d4) {
    const float4 w4 = wsh[e][d4 ^ (e & 7)];
    const float4 s0 = *reinterpret_cast<const float4*>(&srow[rA + 0][d4 * 4]);
    const float4 s1 = *reinterpret_cast<const float4*>(&srow[rA + 1][d4 * 4]);
    acc0 = fmaf(s0.x, w4.x, acc0); acc0 = fmaf(s0.y, w4.y, acc0);
    acc0 = fmaf(s0.z, w4.z, acc0); acc0 = fmaf(s0.w, w4.w, acc0);
    acc1 = fmaf(s1.x, w4.x, acc1); acc1 = fmaf(s1.y, w4.y, acc1);
    acc1 = fmaf(s1.z, w4.z, acc1); acc1 = fmaf(s1.w, w4.w, acc1);
  }

  const float C2 = 2.8853900817779268f;   // 2*log2(e)
  if (!isK) {
    const float bias = bC[e];
    eq[(r0 + rA + 0) * 64 + e] = __builtin_amdgcn_exp2f((acc0 + bias) * C2);
    eq[(r0 + rA + 1) * 64 + e] = __builtin_amdgcn_exp2f((acc1 + bias) * C2);
  } else {
    // transpose in LDS, then coalesced store to ekt[bh][e][k0..k0+7]
    trsp[e][rA + 0] = __builtin_amdgcn_exp2f(acc0 * C2);
    trsp[e][rA + 1] = __builtin_amdgcn_exp2f(acc1 * C2);
    __syncthreads();                       // block-uniform branch: legal
    const int bh = r0 >> 9;
    const int k0 = r0 & 511;
    float* __restrict__ dst = ekt + bh * 64 * 512 + k0;
    #pragma unroll
    for (int iter = 0; iter < 2; ++iter) {
      const int i  = t + iter * 256;
      const int e2 = i >> 3, kk = i & 7;
      dst[e2 * 512 + kk] = trsp[e2][kk];
    }
  }
}

// ---------------- kernel B: fused logits + masked softmax ----------------
// Grid: 2048 blocks; bh = blk&7 (XCD-affine), qp = blk>>3 (0..255);
// 2 q-rows/block, 256 threads. Thread t owns k-pair {2t, 2t+1} for both
// rows (256 evals/thread; block reads the 128KB slab once). q/w staged in
// LDS (broadcast reads). Row spans 4 waves -> shfl reduce + 4-wave LDS
// combine. No-max softmax (|logit| <= sum|2w| ~ 2 -> exp2 safe).
__global__ __launch_bounds__(256) void attn_kernel(
    const float* __restrict__ eq, const float* __restrict__ ekt,
    const float* __restrict__ wl, const int* __restrict__ mask,
    float* __restrict__ out)
{
  const int t  = threadIdx.x;
  const int wv = t >> 6;        // wave 0..3
  const int ln = t & 63;
  const int bh = blockIdx.x & 7;
  const int qp = blockIdx.x >> 3;   // 0..255
  const int b  = bh >> 2;       // H=4
  const int q0 = qp * 2;

  __shared__ float qsh[2][64];
  __shared__ float w2s[64];
  __shared__ float s_sm[4][2], s_sr[4][2];
  __shared__ int   s_any[4][2];

  if (t < 64) w2s[t] = -2.0f * wl[t];
  if (t < 128) qsh[t >> 6][t & 63] = eq[(bh * 512 + q0 + (t >> 6)) * 64 + (t & 63)];
  __syncthreads();

  const f32x2* __restrict__ kq =
      reinterpret_cast<const f32x2*>(ekt + bh * 64 * 512) + t;

  f32x2 a0 = {0.f, 0.f}, a1 = {0.f, 0.f};
  const f32x2 one = {1.f, 1.f};

  // 4 e-terms x 2 k for one q-row: 14 pk-VALU + 2 rcp (8 evals)
#define QK2(AC, QV)                                                           \
  {                                                                           \
    const f32x2 t0 = fma2(s2(QV.x), Ka, one);                                 \
    const f32x2 t1 = fma2(s2(QV.y), Kb, one);                                 \
    const f32x2 t2 = fma2(s2(QV.z), Kc, one);                                 \
    const f32x2 t3 = fma2(s2(QV.w), Kd, one);                                 \
    const f32x2 t01 = t0 * t1, t23 = t2 * t3;                                 \
    const f32x2 den = t01 * t23;                                              \
    const f32x2 n01 = fma2(s2(w4.x), t1, s2(w4.y) * t0);                      \
    const f32x2 n23 = fma2(s2(w4.z), t3, s2(w4.w) * t2);                      \
    const f32x2 num = fma2(n01, t23, n23 * t01);                              \
    f32x2 r;                                                                  \
    r.x = __builtin_amdgcn_rcpf(den.x);                                       \
    r.y = __builtin_amdgcn_rcpf(den.y);                                       \
    AC = fma2(num, r, AC);                                                    \
  }

  #pragma unroll 4
  for (int eb = 0; eb < 16; ++eb) {
    const f32x2 Ka = kq[(eb * 4 + 0) * 256];
    const f32x2 Kb = kq[(eb * 4 + 1) * 256];
    const f32x2 Kc = kq[(eb * 4 + 2) * 256];
    const f32x2 Kd = kq[(eb * 4 + 3) * 256];
    const float4 qa = *reinterpret_cast<const float4*>(&qsh[0][eb * 4]);
    const float4 qb = *reinterpret_cast<const float4*>(&qsh[1][eb * 4]);
    const float4 w4 = *reinterpret_cast<const float4*>(&w2s[eb * 4]);
    QK2(a0, qa)
    QK2(a1, qb)
  }

  // ---- mask (loaded after main loop; not held across it) ----
  const int* __restrict__ mb = mask + (b * 512 + q0) * 512 + 2 * t;
  const int2 mv0 = *reinterpret_cast<const int2*>(mb);
  const int2 mv1 = *reinterpret_cast<const int2*>(mb + 512);

  // ---- no-max softmax: |logit| <= sum|2w| (~2) -> exp2 safe ----
  const float L2E = 1.4426950408889634f;
  f32x2 p0, p1;
  p0.x = __builtin_amdgcn_exp2f(a0.x * L2E);
  p0.y = __builtin_amdgcn_exp2f(a0.y * L2E);
  p1.x = __builtin_amdgcn_exp2f(a1.x * L2E);
  p1.y = __builtin_amdgcn_exp2f(a1.y * L2E);

  float sm0 = (mv0.x ? p0.x : 0.f) + (mv0.y ? p0.y : 0.f);
  float sm1 = (mv1.x ? p1.x : 0.f) + (mv1.y ? p1.y : 0.f);
  float sr0 = p0.x + p0.y;
  float sr1 = p1.x + p1.y;
  const int any0 = __any((mv0.x | mv0.y) != 0) ? 1 : 0;
  const int any1 = __any((mv1.x | mv1.y) != 0) ? 1 : 0;

  #pragma unroll
  for (int s = 1; s < 64; s <<= 1) {
    sm0 += __shfl_xor(sm0, s); sm1 += __shfl_xor(sm1, s);
    sr0 += __shfl_xor(sr0, s); sr1 += __shfl_xor(sr1, s);
  }
  if (ln == 0) {
    s_sm[wv][0] = sm0; s_sm[wv][1] = sm1;
    s_sr[wv][0] = sr0; s_sr[wv][1] = sr1;
    s_any[wv][0] = any0; s_any[wv][1] = any1;
  }
  __syncthreads();

#define ROWOUT(P, MV, I)                                                      \
  {                                                                           \
    const bool ra =                                                           \
        (s_any[0][I] | s_any[1][I] | s_any[2][I] | s_any[3][I]) != 0;         \
    const float sm =                                                          \
        (s_sm[0][I] + s_sm[1][I]) + (s_sm[2][I] + s_sm[3][I]);                \
    const float sr =                                                          \
        (s_sr[0][I] + s_sr[1][I]) + (s_sr[2][I] + s_sr[3][I]);                \
    const float inv = 1.0f / (ra ? sm : sr);                                  \
    float2 o2;                                                                \
    o2.x = ((!ra || MV.x) ? P.x : 0.f) * inv;                                 \
    o2.y = ((!ra || MV.y) ? P.y : 0.f) * inv;                                 \
    *reinterpret_cast<float2*>(                                               \
        out + (bh * 512 + q0 + (I)) * 512 + 2 * t) = o2;                      \
  }
  ROWOUT(p0, mv0, 0)
  ROWOUT(p1, mv1, 1)
}

extern "C" void kernel_launch(void* const* d_in, const int* in_sizes, int n_in,
                              void* d_out, int out_size, void* d_ws, size_t ws_size,
                              hipStream_t stream) {
  const float* Q  = (const float*)d_in[0];
  const float* K  = (const float*)d_in[1];
  // d_in[2] = values : unused by the reference output
  const int*   M  = (const int*)d_in[3];
  const float* W  = (const float*)d_in[4];
  const float* bC = (const float*)d_in[5];
  const float* wl = (const float*)d_in[6];
  // d_in[7] = b_logit : uniform shift, cancels in softmax
  float* out = (float*)d_out;
  float* eqbuf  = (float*)d_ws;            // 4096*64 floats = 1MB
  float* ektbuf = eqbuf + NQROWS * 64;     // 8*64*512 floats = 1MB, transposed

  proj_kernel<<<1024, 256, 0, stream>>>(Q, K, W, bC, eqbuf, ektbuf);
  attn_kernel<<<2048, 256, 0, stream>>>(eqbuf, ektbuf, wl, M, out);
}

// Round 15
// 25.205 us; speedup vs baseline: 1.1680x; 1.1680x over previous
//
#include <hip/hip_runtime.h>
#include <hip/hip_bf16.h>

// Additive attention weights: B=2,H=4,LQ=LKV=512,D=64, fp32 in/out.
//   tanh(x) = 1 - 2/(1+e^{2x});  softmax drops uniform shift (sum w + b_logit)
//   => logit ~ sum_e w'_e/(1+e^{2x_e}),  w' = -2w,  x = qp+kp+b
//   e^{2x} = EQ*EK,  EQ=2^{(qp+b)*2log2e}, EK=2^{kp*2log2e}  (precomputed)
// 4-way rational combine (1 rcp per 4 e-terms). EK stored TRANSPOSED
// [bh][e][k]. attn: 2 q-rows per thread (one EK float4 feeds 8 evals),
// no-max softmax (|logit| <= sum|2w| ~ 2). This is the R8 configuration —
// measured best (25.2 us total). R9-R14 variants (L2/2, pk-math, SGPR-q,
// proj-fusion, occupancy x2, cooperative fusion) were all flat or worse.
// No launch_bounds waves-arg (it forces a 64-VGPR clamp + scratch spill).

#define NQROWS 4096   // B*H*LQ

// ---------------- kernel A: projections + exp2 ----------------
// 8 rows/block: blocks [0,512) Q rows, [512,1024) K rows. 4 waves/block.
__global__ __launch_bounds__(256) void proj_kernel(
    const float* __restrict__ Q, const float* __restrict__ K,
    const float* __restrict__ W, const float* __restrict__ bC,
    float* __restrict__ eq, float* __restrict__ ekt)
{
  const int t  = threadIdx.x;
  const int tr = t >> 6;        // 0..3
  const int e  = t & 63;
  const int rbase = blockIdx.x * 8;
  const bool isK = rbase >= NQROWS;
  const int r0 = isK ? rbase - NQROWS : rbase;
  const float* __restrict__ src = isK ? K : Q;
  const int off = isK ? 64 : 0;

  __shared__ float  srow[8][64];     // 2KB
  __shared__ float4 wsh[64][16];     // 16KB, XOR-swizzled (f4 col ^ (row&7))
  __shared__ float  trsp[64][9];     // 2.3KB, K-store transpose (pad 9)

  for (int i = t; i < 8 * 64; i += 256)
    srow[i >> 6][i & 63] = src[(r0 + (i >> 6)) * 64 + (i & 63)];
  for (int i = t; i < 64 * 16; i += 256) {
    const int er = i >> 4, d4 = i & 15;
    wsh[er][d4 ^ (er & 7)] =
        reinterpret_cast<const float4*>(W + er * 128 + off)[d4];
  }
  __syncthreads();

  float acc0 = 0.f, acc1 = 0.f;
  const int rA = tr * 2;
  #pragma unroll
  for (int d4 = 0; d4 < 16; ++d4) {
    const float4 w4 = wsh[e][d4 ^ (e & 7)];
    const float4 s0 = *reinterpret_cast<const float4*>(&srow[rA + 0][d4 * 4]);
    const float4 s1 = *reinterpret_cast<const float4*>(&srow[rA + 1][d4 * 4]);
    acc0 = fmaf(s0.x, w4.x, acc0); acc0 = fmaf(s0.y, w4.y, acc0);
    acc0 = fmaf(s0.z, w4.z, acc0); acc0 = fmaf(s0.w, w4.w, acc0);
    acc1 = fmaf(s1.x, w4.x, acc1); acc1 = fmaf(s1.y, w4.y, acc1);
    acc1 = fmaf(s1.z, w4.z, acc1); acc1 = fmaf(s1.w, w4.w, acc1);
  }

  const float C2 = 2.8853900817779268f;   // 2*log2(e)
  if (!isK) {
    const float bias = bC[e];
    eq[(r0 + rA + 0) * 64 + e] = __builtin_amdgcn_exp2f((acc0 + bias) * C2);
    eq[(r0 + rA + 1) * 64 + e] = __builtin_amdgcn_exp2f((acc1 + bias) * C2);
  } else {
    // transpose in LDS, then coalesced store to ekt[bh][e][k0..k0+7]
    trsp[e][rA + 0] = __builtin_amdgcn_exp2f(acc0 * C2);
    trsp[e][rA + 1] = __builtin_amdgcn_exp2f(acc1 * C2);
    __syncthreads();                       // block-uniform branch: legal
    const int bh = r0 >> 9;
    const int k0 = r0 & 511;
    float* __restrict__ dst = ekt + bh * 64 * 512 + k0;
    #pragma unroll
    for (int iter = 0; iter < 2; ++iter) {
      const int i  = t + iter * 256;
      const int e2 = i >> 3, kk = i & 7;
      dst[e2 * 512 + kk] = trsp[e2][kk];
    }
  }
}

// ---------------- kernel B: fused logits + masked softmax ----------------
// Grid: 1024 blocks; bh = blk&7 (XCD-affine), qg = blk>>3; 4 q-rows/block.
// 256 threads: g = t>>7 picks q-row pair {q0+2g, q0+2g+1}; c = t&127 is the
// float4 k-column (k = 4c). Each thread: 2 rows x 4 k x 64 e = 512 evals,
// 64 K-float4 loads (8 evals per load). Row's 512 k live on 2 waves ->
// shfl reduce + tiny LDS combine.
__global__ __launch_bounds__(256) void attn_kernel(
    const float* __restrict__ eq, const float* __restrict__ ekt,
    const float* __restrict__ wl, const int* __restrict__ mask,
    float* __restrict__ out)
{
  const int t  = threadIdx.x;
  const int g  = t >> 7;        // q-pair group 0/1
  const int c  = t & 127;       // k float4-column
  const int wv = t >> 6;        // wave 0..3
  const int ln = t & 63;
  const int bh = blockIdx.x & 7;
  const int qg = blockIdx.x >> 3;   // 0..127
  const int b  = bh >> 2;       // H=4
  const int q0 = qg * 4;
  const int r0 = q0 + g * 2;    // this thread's first q-row

  __shared__ float qsh[4][64];
  __shared__ float w2s[64];
  __shared__ float s_sm[4][2], s_sr[4][2];
  __shared__ int   s_any[4][2];

  if (t < 64) w2s[t] = -2.0f * wl[t];
  qsh[t >> 6][t & 63] = eq[(bh * 512 + q0 + (t >> 6)) * 64 + (t & 63)];
  __syncthreads();

  const float4* __restrict__ kq =
      reinterpret_cast<const float4*>(ekt + bh * 64 * 512) + c;

  float4 a0 = {0.f, 0.f, 0.f, 0.f};
  float4 a1 = {0.f, 0.f, 0.f, 0.f};

#define QUADC(AC, QV, C)                                                      \
  {                                                                           \
    const float t0 = fmaf(QV.x, K0.C, 1.f);                                   \
    const float t1 = fmaf(QV.y, K1.C, 1.f);                                   \
    const float t2 = fmaf(QV.z, K2.C, 1.f);                                   \
    const float t3 = fmaf(QV.w, K3.C, 1.f);                                   \
    const float t01 = t0 * t1, t23 = t2 * t3;                                 \
    const float den = t01 * t23;                                              \
    const float n01 = fmaf(w4.x, t1, w4.y * t0);                              \
    const float n23 = fmaf(w4.z, t3, w4.w * t2);                              \
    const float num = fmaf(n01, t23, n23 * t01);                              \
    AC.C = fmaf(num, __builtin_amdgcn_rcpf(den), AC.C);                       \
  }
#define QROW(AC, QV) QUADC(AC, QV, x) QUADC(AC, QV, y) \
                     QUADC(AC, QV, z) QUADC(AC, QV, w)

  #pragma unroll 4
  for (int eb = 0; eb < 16; ++eb) {
    const float4 K0 = kq[(eb * 4 + 0) * 128];
    const float4 K1 = kq[(eb * 4 + 1) * 128];
    const float4 K2 = kq[(eb * 4 + 2) * 128];
    const float4 K3 = kq[(eb * 4 + 3) * 128];
    const float4 qa = *reinterpret_cast<const float4*>(&qsh[g * 2 + 0][eb * 4]);
    const float4 qb = *reinterpret_cast<const float4*>(&qsh[g * 2 + 1][eb * 4]);
    const float4 w4 = *reinterpret_cast<const float4*>(&w2s[eb * 4]);
    QROW(a0, qa) QROW(a1, qb)
  }

  // ---- mask (loaded after main loop; not held across it) ----
  const int* __restrict__ mb = mask + (b * 512 + r0) * 512 + 4 * c;
  const int4 mv0 = *reinterpret_cast<const int4*>(mb);
  const int4 mv1 = *reinterpret_cast<const int4*>(mb + 512);

  // ---- no-max softmax: |logit| <= sum|2w| (~2) -> exp2 safe ----
  const float L2E = 1.4426950408889634f;
  float4 p0, p1;
  p0.x = __builtin_amdgcn_exp2f(a0.x * L2E);
  p0.y = __builtin_amdgcn_exp2f(a0.y * L2E);
  p0.z = __builtin_amdgcn_exp2f(a0.z * L2E);
  p0.w = __builtin_amdgcn_exp2f(a0.w * L2E);
  p1.x = __builtin_amdgcn_exp2f(a1.x * L2E);
  p1.y = __builtin_amdgcn_exp2f(a1.y * L2E);
  p1.z = __builtin_amdgcn_exp2f(a1.z * L2E);
  p1.w = __builtin_amdgcn_exp2f(a1.w * L2E);

  float sm0 = ((mv0.x ? p0.x : 0.f) + (mv0.y ? p0.y : 0.f)) +
              ((mv0.z ? p0.z : 0.f) + (mv0.w ? p0.w : 0.f));
  float sm1 = ((mv1.x ? p1.x : 0.f) + (mv1.y ? p1.y : 0.f)) +
              ((mv1.z ? p1.z : 0.f) + (mv1.w ? p1.w : 0.f));
  float sr0 = (p0.x + p0.y) + (p0.z + p0.w);
  float sr1 = (p1.x + p1.y) + (p1.z + p1.w);
  const int any0 = __any((mv0.x | mv0.y | mv0.z | mv0.w) != 0) ? 1 : 0;
  const int any1 = __any((mv1.x | mv1.y | mv1.z | mv1.w) != 0) ? 1 : 0;

  #pragma unroll
  for (int s = 1; s < 64; s <<= 1) {
    sm0 += __shfl_xor(sm0, s); sm1 += __shfl_xor(sm1, s);
    sr0 += __shfl_xor(sr0, s); sr1 += __shfl_xor(sr1, s);
  }
  if (ln == 0) {
    s_sm[wv][0] = sm0; s_sm[wv][1] = sm1;
    s_sr[wv][0] = sr0; s_sr[wv][1] = sr1;
    s_any[wv][0] = any0; s_any[wv][1] = any1;
  }
  __syncthreads();

  // combine the row's two waves: waves {2g, 2g+1}
  const int wA = g * 2, wB = g * 2 + 1;
  const bool ra0 = (s_any[wA][0] | s_any[wB][0]) != 0;
  const bool ra1 = (s_any[wA][1] | s_any[wB][1]) != 0;
  const float inv0 =
      1.0f / (ra0 ? (s_sm[wA][0] + s_sm[wB][0]) : (s_sr[wA][0] + s_sr[wB][0]));
  const float inv1 =
      1.0f / (ra1 ? (s_sm[wA][1] + s_sm[wB][1]) : (s_sr[wA][1] + s_sr[wB][1]));

  float4 o0, o1;
  o0.x = ((!ra0 || mv0.x) ? p0.x : 0.f) * inv0;
  o0.y = ((!ra0 || mv0.y) ? p0.y : 0.f) * inv0;
  o0.z = ((!ra0 || mv0.z) ? p0.z : 0.f) * inv0;
  o0.w = ((!ra0 || mv0.w) ? p0.w : 0.f) * inv0;
  o1.x = ((!ra1 || mv1.x) ? p1.x : 0.f) * inv1;
  o1.y = ((!ra1 || mv1.y) ? p1.y : 0.f) * inv1;
  o1.z = ((!ra1 || mv1.z) ? p1.z : 0.f) * inv1;
  o1.w = ((!ra1 || mv1.w) ? p1.w : 0.f) * inv1;

  float* __restrict__ o = out + (bh * 512 + r0) * 512 + 4 * c;
  *reinterpret_cast<float4*>(o) = o0;
  *reinterpret_cast<float4*>(o + 512) = o1;
}

extern "C" void kernel_launch(void* const* d_in, const int* in_sizes, int n_in,
                              void* d_out, int out_size, void* d_ws, size_t ws_size,
                              hipStream_t stream) {
  const float* Q  = (const float*)d_in[0];
  const float* K  = (const float*)d_in[1];
  // d_in[2] = values : unused by the reference output
  const int*   M  = (const int*)d_in[3];
  const float* W  = (const float*)d_in[4];
  const float* bC = (const float*)d_in[5];
  const float* wl = (const float*)d_in[6];
  // d_in[7] = b_logit : uniform shift, cancels in softmax
  float* out = (float*)d_out;
  float* eqbuf  = (float*)d_ws;            // 4096*64 floats = 1MB
  float* ektbuf = eqbuf + NQROWS * 64;     // 8*64*512 floats = 1MB, transposed

  proj_kernel<<<1024, 256, 0, stream>>>(Q, K, W, bC, eqbuf, ektbuf);
  attn_kernel<<<1024, 256, 0, stream>>>(eqbuf, ektbuf, wl, M, out);
}